// Round 2
// baseline (1007.781 us; speedup 1.0000x reference)
//
#include <hip/hip_runtime.h>

// DCNv2: B=4, C=256, H=W=64, OC=256, K=9 (3x3), stride=1, pad=1, dil=1.
// Pipeline: wprep (weight transpose) -> offs_conv -> coords -> main_conv.

#define NB 4
#define NC 256
#define HW 64
#define NP 4096          // 64*64
#define NOC 256
#define NK 9
#define NCK 2304         // NC*NK

// ---------------------------------------------------------------- wprep
// Wt[(k*256+c)*256 + o] = weight[o*2304 + c*9 + k]
__global__ __launch_bounds__(256) void wprep(const float* __restrict__ w,
                                             float* __restrict__ wt) {
    int e = blockIdx.x * 256 + threadIdx.x;   // e < 2304*256
    int o  = e & 255;
    int ck = e >> 8;        // k*256 + c
    int c  = ck & 255;
    int k  = ck >> 8;
    wt[e] = w[o * NCK + c * 9 + k];
}

// ---------------------------------------------------------------- offset conv
// om[b][ch][y][x] = sum_{c,i,j} x[b][c][y+i-1][x+j-1] * ow[ch][c][i][j] + obias[ch]
// Block = (b, y). 256 threads = 4 waves; lane = ox (row == 64 lanes!),
// wave cg owns channels {cg + 4q}. j-shifts via shuffles (zero pad at edges).
__global__ __launch_bounds__(256) void offs_conv(const float* __restrict__ x,
                                                 const float* __restrict__ ow,
                                                 const float* __restrict__ obias,
                                                 float* __restrict__ om) {
    int b = blockIdx.x >> 6;
    int y = blockIdx.x & 63;
    int lane = threadIdx.x & 63;
    int cg = __builtin_amdgcn_readfirstlane(threadIdx.x >> 6);  // wave-uniform

    float acc[7];
    #pragma unroll
    for (int q = 0; q < 7; ++q) acc[q] = 0.f;

    const float* xb = x + b * NC * NP;
    for (int c = 0; c < NC; ++c) {
        const float* xc = xb + c * NP;
        #pragma unroll
        for (int i = 0; i < 3; ++i) {
            int row = y + i - 1;
            float v = 0.f;
            if (row >= 0 && row < HW) v = xc[row * HW + lane];
            float vl = __shfl_up(v, 1);
            if (lane == 0) vl = 0.f;
            float vr = __shfl_down(v, 1);
            if (lane == 63) vr = 0.f;
            #pragma unroll
            for (int q = 0; q < 7; ++q) {
                int ch = cg + 4 * q;
                if (ch < 27) {
                    const float* wp = ow + (ch * NC + c) * 9 + i * 3;
                    acc[q] += wp[0] * vl + wp[1] * v + wp[2] * vr;
                }
            }
        }
    }
    #pragma unroll
    for (int q = 0; q < 7; ++q) {
        int ch = cg + 4 * q;
        if (ch < 27)
            om[(b * 27 + ch) * NP + y * HW + lane] = acc[q] + obias[ch];
    }
}

// ---------------------------------------------------------------- coords
// Per (b,k,p): 4 bilinear corner plane-indices (clamped) and weights
// (corner_wgt * validity * sigmoid(mask)).
__global__ __launch_bounds__(256) void coords(const float* __restrict__ om,
                                              int4* __restrict__ cidx,
                                              float4* __restrict__ cw) {
    int g = blockIdx.x * 256 + threadIdx.x;   // < 4*9*4096
    int p  = g & 4095;
    int bk = g >> 12;
    int k  = bk % 9;
    int b  = bk / 9;

    float o1 = om[(b * 27 + k) * NP + p];
    float o2 = om[(b * 27 + 9 + k) * NP + p];
    float ml = om[(b * 27 + 18 + k) * NP + p];
    float mask = 1.f / (1.f + expf(-ml));

    float ox = (float)(p & 63);
    float oy = (float)(p >> 6);
    // sx = ox - PAD + gx[k] + offx, gx = (k%3)-1  ->  ox + (k%3) - 2 + offx
    float sx = ox + (float)(k % 3) - 2.0f + o1;
    float sy = oy + (float)(k / 3) - 2.0f + o2;

    float x0 = floorf(sx), y0 = floorf(sy);
    float fx = sx - x0, fy = sy - y0;
    float wxs[2] = {1.f - fx, fx};
    float wys[2] = {1.f - fy, fy};
    float xs[2]  = {x0, x0 + 1.f};
    float ys[2]  = {y0, y0 + 1.f};

    int idx[4]; float wgt[4];
    #pragma unroll
    for (int cy = 0; cy < 2; ++cy) {
        #pragma unroll
        for (int cx = 0; cx < 2; ++cx) {
            float xf = xs[cx], yf = ys[cy];
            bool valid = (xf >= 0.f) & (xf <= 63.f) & (yf >= 0.f) & (yf <= 63.f);
            int xi = (int)fminf(fmaxf(xf, 0.f), 63.f);
            int yi = (int)fminf(fmaxf(yf, 0.f), 63.f);
            int q = cy * 2 + cx;
            idx[q] = yi * HW + xi;
            wgt[q] = valid ? wxs[cx] * wys[cy] * mask : 0.f;
        }
    }
    cidx[g] = make_int4(idx[0], idx[1], idx[2], idx[3]);
    cw[g]   = make_float4(wgt[0], wgt[1], wgt[2], wgt[3]);
}

// ---------------------------------------------------------------- main conv
// Block = (b, y, ob): O_tile=128 (ob half), P_tile=64 (row y). 256 threads.
// Thread t: to=t&63 owns o = ob*128 + i*64 + to (i<2); tp=t>>6 owns p=tp*16+j.
// LDS: coords (all 9 k for 64 p), Wt tile [16][128], S tile [16][64].
__global__ __launch_bounds__(256) void main_conv(const float* __restrict__ x,
                                                 const float* __restrict__ wt,
                                                 const int4* __restrict__ cidx,
                                                 const float4* __restrict__ cw,
                                                 const float* __restrict__ bias,
                                                 float* __restrict__ out) {
    __shared__ __align__(16) char smem[30720];
    int4*   ci_lds = (int4*)smem;                  // [9][64]   9216 B
    float4* cw_lds = (float4*)(smem + 9216);       // [9][64]   9216 B
    float*  wt_lds = (float*)(smem + 18432);       // [16][128] 8192 B
    float*  s_lds  = (float*)(smem + 26624);       // [16][64]  4096 B

    int bid = blockIdx.x;
    int ob = bid & 1;
    int y  = (bid >> 1) & 63;
    int b  = bid >> 7;
    int t  = threadIdx.x;
    int to = t & 63;
    int tp = t >> 6;

    // Stage coords for this row: 9 k x 64 p
    for (int e = t; e < 9 * 64; e += 256) {
        int kk = e >> 6, pp = e & 63;
        int src = (b * 9 + kk) * NP + y * HW + pp;
        ci_lds[kk * 64 + pp] = cidx[src];
        cw_lds[kk * 64 + pp] = cw[src];
    }
    __syncthreads();

    float acc[2][16];
    #pragma unroll
    for (int i = 0; i < 2; ++i)
        #pragma unroll
        for (int j = 0; j < 16; ++j) acc[i][j] = 0.f;

    const float* xb = x + b * NC * NP;

    for (int tile = 0; tile < NCK / 16; ++tile) {   // 144 tiles
        int ck0 = tile * 16;
        int k   = ck0 >> 8;
        int c0  = ck0 & 255;

        // stage Wt[ck0..+16][ob*128..+128]
        {
            int ci = t >> 5;            // 0..7
            int oo = (t & 31) * 4;      // 0..124
            const float* src = wt + ck0 * 256 + ob * 128;
            *(float4*)&wt_lds[ci * 128 + oo]       = *(const float4*)&src[ci * 256 + oo];
            *(float4*)&wt_lds[(ci + 8) * 128 + oo] = *(const float4*)&src[(ci + 8) * 256 + oo];
        }
        // stage S[16][64]: thread builds 4 elements (ci0+4u, p)
        {
            int p   = t & 63;
            int ci0 = t >> 6;           // 0..3
            int4   id4 = ci_lds[k * 64 + p];
            float4 w4  = cw_lds[k * 64 + p];
            #pragma unroll
            for (int u = 0; u < 4; ++u) {
                int ci = ci0 + u * 4;
                const float* xc = xb + (c0 + ci) * NP;
                float s = w4.x * xc[id4.x] + w4.y * xc[id4.y]
                        + w4.z * xc[id4.z] + w4.w * xc[id4.w];
                s_lds[ci * 64 + p] = s;
            }
        }
        __syncthreads();

        #pragma unroll
        for (int ci = 0; ci < 16; ++ci) {
            float w0 = wt_lds[ci * 128 + to];
            float w1 = wt_lds[ci * 128 + 64 + to];
            const float4* srow = (const float4*)&s_lds[ci * 64 + tp * 16];
            #pragma unroll
            for (int j4 = 0; j4 < 4; ++j4) {
                float4 sv = srow[j4];
                acc[0][j4 * 4 + 0] += w0 * sv.x;
                acc[0][j4 * 4 + 1] += w0 * sv.y;
                acc[0][j4 * 4 + 2] += w0 * sv.z;
                acc[0][j4 * 4 + 3] += w0 * sv.w;
                acc[1][j4 * 4 + 0] += w1 * sv.x;
                acc[1][j4 * 4 + 1] += w1 * sv.y;
                acc[1][j4 * 4 + 2] += w1 * sv.z;
                acc[1][j4 * 4 + 3] += w1 * sv.w;
            }
        }
        __syncthreads();
    }

    // Epilogue: LDS transpose for coalesced stores (reuses coord region).
    float* trans = (float*)smem;   // [64][65] = 16640 B
    for (int i = 0; i < 2; ++i) {
        __syncthreads();
        #pragma unroll
        for (int j = 0; j < 16; ++j)
            trans[to * 65 + tp * 16 + j] = acc[i][j];
        __syncthreads();
        #pragma unroll
        for (int r = 0; r < 16; ++r) {
            int row = r * 4 + tp;                    // 0..63
            float v = trans[row * 65 + to];
            int o = ob * 128 + i * 64 + row;
            out[((b * NOC + o) << 12) + y * HW + to] = v + bias[o];
        }
    }
}

// ---------------------------------------------------------------- launch
extern "C" void kernel_launch(void* const* d_in, const int* in_sizes, int n_in,
                              void* d_out, int out_size, void* d_ws, size_t ws_size,
                              hipStream_t stream) {
    const float* x     = (const float*)d_in[0];
    const float* ow    = (const float*)d_in[1];
    const float* obias = (const float*)d_in[2];
    const float* w     = (const float*)d_in[3];
    const float* bias  = (const float*)d_in[4];
    float* out = (float*)d_out;

    char* ws = (char*)d_ws;
    float* om  = (float*)ws;                         // 4*27*4096*4   = 1,769,472 B
    int4*  ci  = (int4*)(ws + 1769472);              // 147456*16     = 2,359,296 B
    float4* cw = (float4*)(ws + 1769472 + 2359296);  // 147456*16     = 2,359,296 B
    float* wt  = (float*)(ws + 1769472 + 2 * 2359296); // 2304*256*4  = 2,359,296 B

    hipLaunchKernelGGL(wprep,     dim3(2304), dim3(256), 0, stream, w, wt);
    hipLaunchKernelGGL(offs_conv, dim3(256),  dim3(256), 0, stream, x, ow, obias, om);
    hipLaunchKernelGGL(coords,    dim3(576),  dim3(256), 0, stream, om, ci, cw);
    hipLaunchKernelGGL(main_conv, dim3(512),  dim3(256), 0, stream, x, wt, ci, cw, bias, out);
}

// Round 3
// 349.578 us; speedup vs baseline: 2.8828x; 2.8828x over previous
//
#include <hip/hip_runtime.h>

// DCNv2 B=4,C=256,H=W=64,OC=256,K=9. Pipeline:
//   wprep_A  : weight -> WtA[o][ck] bf16 (ck = k*256+c), rows 4608 B
//   owt_prep : offset_w -> owT[(c*3+i)*81 + ch*3 + j] f32 (per-(c,i) contiguous)
//   om_init  : om = obias broadcast
//   offs_conv2: 3x3 conv, c-split x8, LDS reduce + atomicAdd -> om
//   gather   : coords(once per k,p) + bilinear*mask over all c -> S[b][p][ck] bf16
//   gemm     : bf16 MFMA 16x16x32, out[o][p] = WtA . S + bias

#define NB 4
#define NC 256
#define HW 64
#define NP 4096
#define NOC 256
#define NCK 2304
#define NKT 72              // K tiles of 32
#define ROWB 4608           // bytes per ck-row (2304 * 2B)

typedef __attribute__((ext_vector_type(8))) short short8;
typedef __attribute__((ext_vector_type(4))) float f32x4;
typedef unsigned short ushort_t;
typedef unsigned int uint32;

__device__ __forceinline__ void gload16(const void* g, void* l) {
    __builtin_amdgcn_global_load_lds(
        (const __attribute__((address_space(1))) unsigned int*)g,
        (__attribute__((address_space(3))) unsigned int*)l, 16, 0, 0);
}

__device__ __forceinline__ uint32 f2bf(float v) {
    uint32 b = __float_as_uint(v);
    return (b + 0x7FFFu + ((b >> 16) & 1u)) >> 16;   // RNE
}

// ---------------------------------------------------------------- wprep_A
// WtA[o*2304 + ck] = bf16(weight[o][c][k]), ck = k*256 + c
__global__ __launch_bounds__(256) void wprep_A(const float* __restrict__ w,
                                               ushort_t* __restrict__ wta) {
    int e = blockIdx.x * 256 + threadIdx.x;     // < 256*2304
    int o  = e / NCK;
    int ck = e - o * NCK;
    int c = ck & 255;
    int k = ck >> 8;
    wta[e] = (ushort_t)f2bf(w[o * NCK + c * 9 + k]);
}

// ---------------------------------------------------------------- owt_prep
__global__ __launch_bounds__(256) void owt_prep(const float* __restrict__ ow,
                                                float* __restrict__ owt) {
    int e = blockIdx.x * 256 + threadIdx.x;     // < 256*243
    int c = e / 243;
    int r = e - c * 243;
    int i = r / 81;
    int s = r - i * 81;
    int ch = s / 3;
    int j  = s - ch * 3;
    owt[e] = ow[((ch * NC + c) * 3 + i) * 3 + j];
}

// ---------------------------------------------------------------- om_init
__global__ __launch_bounds__(256) void om_init(const float* __restrict__ obias,
                                               float* __restrict__ om) {
    int g = blockIdx.x * 256 + threadIdx.x;     // < 4*27*4096
    int r = g >> 12;          // b*27 + ch
    int ch = r % 27;
    om[g] = obias[ch];
}

// ---------------------------------------------------------------- offs_conv2
// Block = (b, y, cs): cs-th 32-channel slice. 4 waves x 8 c each, lane = x.
__global__ __launch_bounds__(256) void offs_conv2(const float* __restrict__ x,
                                                  const float* __restrict__ owt,
                                                  float* __restrict__ om) {
    __shared__ float red[4 * 27 * 64];
    int bid = blockIdx.x;
    int cs = bid & 7;
    int y  = (bid >> 3) & 63;
    int b  = bid >> 9;
    int t = threadIdx.x;
    int lane = t & 63;
    int w = t >> 6;

    float acc[27];
    #pragma unroll
    for (int ch = 0; ch < 27; ++ch) acc[ch] = 0.f;

    int c0 = cs * 32 + w * 8;
    const float* xb = x + (size_t)b * NC * NP;
    for (int cc = 0; cc < 8; ++cc) {
        int c = c0 + cc;
        const float* xc = xb + (size_t)c * NP;
        const float* wb = owt + (size_t)c * 243;
        #pragma unroll
        for (int i = 0; i < 3; ++i) {
            int row = y + i - 1;
            float v = 0.f;
            if (row >= 0 && row < HW) v = xc[row * HW + lane];
            float vl = __shfl_up(v, 1);   if (lane == 0)  vl = 0.f;
            float vr = __shfl_down(v, 1); if (lane == 63) vr = 0.f;
            const float* wi = wb + i * 81;
            #pragma unroll
            for (int ch = 0; ch < 27; ++ch)
                acc[ch] += wi[ch*3+0] * vl + wi[ch*3+1] * v + wi[ch*3+2] * vr;
        }
    }
    #pragma unroll
    for (int ch = 0; ch < 27; ++ch) red[(w * 27 + ch) * 64 + lane] = acc[ch];
    __syncthreads();
    for (int e = t; e < 27 * 64; e += 256) {
        int ch = e >> 6, xl = e & 63;
        float s = red[ch * 64 + xl] + red[(27 + ch) * 64 + xl]
                + red[(54 + ch) * 64 + xl] + red[(81 + ch) * 64 + xl];
        atomicAdd(&om[((size_t)(b * 27 + ch)) * NP + y * HW + xl], s);
    }
}

// ---------------------------------------------------------------- gather
// Block = (b,k,y). Coords once per (k,p); each wave covers 64 c; write bf16
// S[b][p][ck] (ck = k*256+c) as 4x dwordx4 per 32-c chunk.
__global__ __launch_bounds__(256) void gather(const float* __restrict__ x,
                                              const float* __restrict__ om,
                                              ushort_t* __restrict__ sb) {
    int bid = blockIdx.x;            // b*576 + k*64 + y
    int y = bid & 63;
    int k = (bid >> 6) % 9;
    int b = bid / 576;
    int t = threadIdx.x;
    int lane = t & 63;
    int w = t >> 6;
    int p = y * HW + lane;

    const float* omb = om + ((size_t)b * 27) * NP;
    float o1 = omb[(size_t)k * NP + p];
    float o2 = omb[(size_t)(9 + k) * NP + p];
    float ml = omb[(size_t)(18 + k) * NP + p];
    float mask = 1.f / (1.f + expf(-ml));

    float sx = (float)lane + (float)(k % 3) - 2.0f + o1;
    float sy = (float)y    + (float)(k / 3) - 2.0f + o2;
    float x0f = floorf(sx), y0f = floorf(sy);
    float fx = sx - x0f, fy = sy - y0f;

    int idx[4]; float wgt[4];
    #pragma unroll
    for (int cy = 0; cy < 2; ++cy) {
        float yf = y0f + (float)cy;
        float wy = cy ? fy : 1.f - fy;
        #pragma unroll
        for (int cx = 0; cx < 2; ++cx) {
            float xf = x0f + (float)cx;
            float wx = cx ? fx : 1.f - fx;
            bool valid = (xf >= 0.f) && (xf <= 63.f) && (yf >= 0.f) && (yf <= 63.f);
            int xi = min(max((int)xf, 0), 63);
            int yi = min(max((int)yf, 0), 63);
            idx[cy * 2 + cx] = yi * HW + xi;
            wgt[cy * 2 + cx] = valid ? wx * wy * mask : 0.f;
        }
    }

    const float* xb = x + (size_t)b * NC * NP;
    ushort_t* rowp = sb + (size_t)b * NP * NCK + (size_t)p * NCK;
    #pragma unroll
    for (int half = 0; half < 2; ++half) {
        int cb = w * 64 + half * 32;
        int ck0 = k * 256 + cb;
        #pragma unroll
        for (int g = 0; g < 4; ++g) {
            uint32 pk[4];
            #pragma unroll
            for (int qq = 0; qq < 4; ++qq) {
                int c = cb + g * 8 + qq * 2;
                const float* xc0 = xb + (size_t)c * NP;
                const float* xc1 = xc0 + NP;
                float s0 = wgt[0]*xc0[idx[0]] + wgt[1]*xc0[idx[1]]
                         + wgt[2]*xc0[idx[2]] + wgt[3]*xc0[idx[3]];
                float s1 = wgt[0]*xc1[idx[0]] + wgt[1]*xc1[idx[1]]
                         + wgt[2]*xc1[idx[2]] + wgt[3]*xc1[idx[3]];
                pk[qq] = f2bf(s0) | (f2bf(s1) << 16);
            }
            *(int4*)(rowp + ck0 + g * 8) =
                make_int4((int)pk[0], (int)pk[1], (int)pk[2], (int)pk[3]);
        }
    }
}

// ---------------------------------------------------------------- gemm
// Block = (b, ot, pt): 128 o x 128 p tile. 4 waves; wave = 64o x 64p = 16 frags.
// LDS tiles [128 rows][80 B] (64 B real k-data + 16 B pad) -> conflict-free b128.
__global__ __launch_bounds__(256) void gemm(const ushort_t* __restrict__ wta,
                                            const ushort_t* __restrict__ sb,
                                            const float* __restrict__ bias,
                                            float* __restrict__ out) {
    __shared__ __align__(16) char lds[2 * 20480];   // [buf][A 10240 | B 10240]
    int bid = blockIdx.x;           // b*64 + ot*32 + pt
    int pt = bid & 31;
    int ot = (bid >> 5) & 1;
    int b  = bid >> 6;
    int t = threadIdx.x;
    int lane = t & 63;
    int w = t >> 6;
    int oh = (w & 1) * 64;
    int ph = (w >> 1) * 64;
    int r16 = lane & 15;
    int g   = lane >> 4;

    const char* Abase = (const char*)wta + (size_t)(ot * 128) * ROWB;
    const char* Bbase = (const char*)sb + (size_t)b * NP * ROWB
                                        + (size_t)(pt * 128) * ROWB;
    // 10 x 1024B staging insts per matrix; wave w gets j = w, w+4, w+8 (<10).
    int nj = (w < 2) ? 3 : 2;
    const char* srcA[3]; const char* srcB[3]; int doff[3];
    #pragma unroll
    for (int jj = 0; jj < 3; ++jj) {
        int j = w + jj * 4;
        if (j < 10) {
            int d = j * 1024 + lane * 16;
            int pl = d / 80;            // LDS row (80 B rows)
            int c  = d - pl * 80;       // in {0,16,32,48,64}
            if (c >= 64) c = 48;        // pad chunk: re-read real data
            srcA[jj] = Abase + (size_t)pl * ROWB + c;
            srcB[jj] = Bbase + (size_t)pl * ROWB + c;
            doff[jj] = j * 1024;
        } else { srcA[jj] = Abase; srcB[jj] = Bbase; doff[jj] = 0; }
    }

    int aoff[4], boff[4];
    #pragma unroll
    for (int f = 0; f < 4; ++f) {
        aoff[f] = (oh + f * 16 + r16) * 80 + g * 16;
        boff[f] = 10240 + (ph + f * 16 + r16) * 80 + g * 16;
    }

    f32x4 acc[4][4];
    #pragma unroll
    for (int fo = 0; fo < 4; ++fo)
        #pragma unroll
        for (int fp = 0; fp < 4; ++fp) acc[fo][fp] = (f32x4){0.f, 0.f, 0.f, 0.f};

    // stage kt=0 into buf 0
    #pragma unroll
    for (int jj = 0; jj < 3; ++jj)
        if (jj < nj) {
            gload16(srcA[jj], lds + doff[jj]);
            gload16(srcB[jj], lds + 10240 + doff[jj]);
        }
    __syncthreads();

    for (int kt = 0; kt < NKT; ++kt) {
        int q = kt & 1;
        if (kt + 1 < NKT) {
            char* dst = lds + (q ^ 1) * 20480;
            size_t ko = (size_t)(kt + 1) * 64;
            #pragma unroll
            for (int jj = 0; jj < 3; ++jj)
                if (jj < nj) {
                    gload16(srcA[jj] + ko, dst + doff[jj]);
                    gload16(srcB[jj] + ko, dst + 10240 + doff[jj]);
                }
        }
        const char* buf = lds + q * 20480;
        short8 av[4], bv[4];
        #pragma unroll
        for (int f = 0; f < 4; ++f) {
            av[f] = *(const short8*)(buf + aoff[f]);
            bv[f] = *(const short8*)(buf + boff[f]);
        }
        #pragma unroll
        for (int fo = 0; fo < 4; ++fo)
            #pragma unroll
            for (int fp = 0; fp < 4; ++fp)
                acc[fo][fp] = __builtin_amdgcn_mfma_f32_16x16x32_bf16(
                    av[fo], bv[fp], acc[fo][fp], 0, 0, 0);
        __syncthreads();
    }

    // epilogue: C/D layout col=lane&15 (p), row=(lane>>4)*4+reg (o)
    int obase = ot * 128 + oh;
    int pbase = pt * 128 + ph + r16;
    float* outb = out + ((size_t)b * NOC) * NP;
    #pragma unroll
    for (int fo = 0; fo < 4; ++fo) {
        #pragma unroll
        for (int r = 0; r < 4; ++r) {
            int o = obase + fo * 16 + g * 4 + r;
            float bb = bias[o];
            #pragma unroll
            for (int fp = 0; fp < 4; ++fp)
                outb[(size_t)o * NP + pbase + fp * 16] = acc[fo][fp][r] + bb;
        }
    }
}

// ---------------------------------------------------------------- launch
extern "C" void kernel_launch(void* const* d_in, const int* in_sizes, int n_in,
                              void* d_out, int out_size, void* d_ws, size_t ws_size,
                              hipStream_t stream) {
    const float* x     = (const float*)d_in[0];
    const float* ow    = (const float*)d_in[1];
    const float* obias = (const float*)d_in[2];
    const float* wgt   = (const float*)d_in[3];
    const float* bias  = (const float*)d_in[4];
    float* out = (float*)d_out;

    char* ws = (char*)d_ws;
    float*    om   = (float*)ws;                    // 1,769,472 B
    float*    owt  = (float*)(ws + 1769472);        //   248,832 B
    ushort_t* wta  = (ushort_t*)(ws + 2018304);     // 1,179,648 B
    ushort_t* sbuf = (ushort_t*)(ws + 3197952);     // 75,497,472 B (tot ~78.7 MB)

    hipLaunchKernelGGL(wprep_A,    dim3(2304), dim3(256), 0, stream, wgt, wta);
    hipLaunchKernelGGL(owt_prep,   dim3(243),  dim3(256), 0, stream, ow, owt);
    hipLaunchKernelGGL(om_init,    dim3(1728), dim3(256), 0, stream, obias, om);
    hipLaunchKernelGGL(offs_conv2, dim3(2048), dim3(256), 0, stream, x, owt, om);
    hipLaunchKernelGGL(gather,     dim3(2304), dim3(256), 0, stream, x, om, sbuf);
    hipLaunchKernelGGL(gemm,       dim3(256),  dim3(256), 0, stream, wta, sbuf, bias, out);
}

// Round 5
// 250.508 us; speedup vs baseline: 4.0230x; 1.3955x over previous
//
#include <hip/hip_runtime.h>

// DCNv2 B=4,C=256,H=W=64,OC=256,K=9. Pipeline:
//   wprep_A   : weight -> WtA[o][ck] bf16 (ck=k*256+c)
//   owt_prep  : offset_w -> owt[(c*3+i)*81 + ch*3+j] f32
//   om_init   : om = obias broadcast
//   xprep     : x NCHW f32 -> xT[b][p][c] bf16 (NHWC)
//   offs_conv3: 3x3 conv c-split x8, scalar weights, global atomics -> om
//   gather2   : coords once per (k,p); lane=c coalesced bf16 gather -> S[b][p][ck]
//   gemm2     : bf16 MFMA 16x16x32, 128o x 64p tiles, grid 512

#define NB 4
#define NC 256
#define HW 64
#define NP 4096
#define NOC 256
#define NCK 2304
#define NKT 72              // K tiles of 32
#define ROWB 4608           // bytes per ck-row (2304 * 2B)

typedef __attribute__((ext_vector_type(8))) short short8;
typedef __attribute__((ext_vector_type(4))) float f32x4;
typedef unsigned short ushort_t;
typedef unsigned int uint32;

__device__ __forceinline__ void gload16(const void* g, void* l) {
    __builtin_amdgcn_global_load_lds(
        (const __attribute__((address_space(1))) unsigned int*)g,
        (__attribute__((address_space(3))) unsigned int*)l, 16, 0, 0);
}

__device__ __forceinline__ uint32 f2bf(float v) {
    uint32 b = __float_as_uint(v);
    return (b + 0x7FFFu + ((b >> 16) & 1u)) >> 16;   // RNE
}
__device__ __forceinline__ float bf_lo(uint32 u) { return __uint_as_float(u << 16); }
__device__ __forceinline__ float bf_hi(uint32 u) { return __uint_as_float(u & 0xFFFF0000u); }

// ---------------------------------------------------------------- wprep_A
__global__ __launch_bounds__(256) void wprep_A(const float* __restrict__ w,
                                               ushort_t* __restrict__ wta) {
    int e = blockIdx.x * 256 + threadIdx.x;     // < 256*2304
    int o  = e / NCK;
    int ck = e - o * NCK;
    int c = ck & 255;
    int k = ck >> 8;
    wta[e] = (ushort_t)f2bf(w[o * NCK + c * 9 + k]);
}

// ---------------------------------------------------------------- owt_prep
__global__ __launch_bounds__(256) void owt_prep(const float* __restrict__ ow,
                                                float* __restrict__ owt) {
    int e = blockIdx.x * 256 + threadIdx.x;     // < 256*243
    int c = e / 243;
    int r = e - c * 243;
    int i = r / 81;
    int s = r - i * 81;
    int ch = s / 3;
    int j  = s - ch * 3;
    owt[e] = ow[((ch * NC + c) * 3 + i) * 3 + j];
}

// ---------------------------------------------------------------- om_init
__global__ __launch_bounds__(256) void om_init(const float* __restrict__ obias,
                                               float* __restrict__ om) {
    int g = blockIdx.x * 256 + threadIdx.x;     // < 4*27*4096
    int r = g >> 12;
    int ch = r % 27;
    om[g] = obias[ch];
}

// ---------------------------------------------------------------- xprep
// xT[b][p][c] bf16. Block=(b,y,rep): thread (c8=t&31, pl=rep*8+(t>>5)).
// Writes: wave = 2 p-rows x 512B = 1024B contiguous. Reads coalesce via L1 reuse.
__global__ __launch_bounds__(256) void xprep(const float* __restrict__ x,
                                             ushort_t* __restrict__ xt) {
    int bid = blockIdx.x;            // b*512 + y*8 + rep
    int rep = bid & 7;
    int y   = (bid >> 3) & 63;
    int b   = bid >> 9;
    int t = threadIdx.x;
    int c8 = t & 31;
    int pl = rep * 8 + (t >> 5);
    int p = y * HW + pl;
    const float* xp = x + ((size_t)b * NC) * NP + p;
    uint32 pk[4];
    #pragma unroll
    for (int h = 0; h < 4; ++h) {
        float v0 = xp[(size_t)(c8 * 8 + 2 * h)     * NP];
        float v1 = xp[(size_t)(c8 * 8 + 2 * h + 1) * NP];
        pk[h] = f2bf(v0) | (f2bf(v1) << 16);
    }
    *(int4*)(xt + ((size_t)b * NP + p) * NC + c8 * 8) =
        make_int4((int)pk[0], (int)pk[1], (int)pk[2], (int)pk[3]);
}

// ---------------------------------------------------------------- offs_conv3
// Block=(b,y,cs). 4 waves x 8 c each, lane=x. Weight base made wave-uniform
// via readfirstlane -> scalar (s_load) weights. Direct coalesced global atomics.
__global__ __launch_bounds__(256) void offs_conv3(const float* __restrict__ x,
                                                  const float* __restrict__ owt,
                                                  float* __restrict__ om) {
    int bid = blockIdx.x;
    int cs = bid & 7;
    int y  = (bid >> 3) & 63;
    int b  = bid >> 9;
    int t = threadIdx.x;
    int lane = t & 63;
    int w = __builtin_amdgcn_readfirstlane(t >> 6);
    int c0 = cs * 32 + w * 8;

    float acc[27];
    #pragma unroll
    for (int ch = 0; ch < 27; ++ch) acc[ch] = 0.f;

    const float* xb = x + (size_t)b * NC * NP;
    #pragma unroll 1
    for (int cc = 0; cc < 8; ++cc) {
        int c = c0 + cc;
        const float* xc = xb + (size_t)c * NP;
        const float* wb = owt + (size_t)c * 243;
        #pragma unroll
        for (int i = 0; i < 3; ++i) {
            int row = y + i - 1;
            float v = (row >= 0 && row < HW) ? xc[row * HW + lane] : 0.f;
            float vl = __shfl_up(v, 1);   if (lane == 0)  vl = 0.f;
            float vr = __shfl_down(v, 1); if (lane == 63) vr = 0.f;
            const float* wi = wb + i * 81;
            #pragma unroll
            for (int ch = 0; ch < 27; ++ch)
                acc[ch] += wi[ch*3+0] * vl + wi[ch*3+1] * v + wi[ch*3+2] * vr;
        }
    }
    float* omr = om + ((size_t)b * 27) * NP + y * HW + lane;
    #pragma unroll
    for (int ch = 0; ch < 27; ++ch)
        atomicAdd(omr + (size_t)ch * NP, acc[ch]);
}

// ---------------------------------------------------------------- gather2
// Block=(b,k,y) with XCD affinity: batch b pinned to XCDs {2b,2b+1}.
// Phase 1: threads 0..63 compute coords for the row's 64 p.
// Phase 2: lane=c (4 c per lane), wave w owns p-lanes w*16..+16.
// All corner loads 512B coalesced from bf16 NHWC xT; stores 512B coalesced.
__global__ __launch_bounds__(256) void gather2(const ushort_t* __restrict__ xt,
                                               const float* __restrict__ om,
                                               ushort_t* __restrict__ sb) {
    __shared__ __align__(16) int   ci_l[64 * 4];
    __shared__ __align__(16) float cw_l[64 * 4];
    int g = blockIdx.x;                    // 2304 blocks
    int b = (g & 7) >> 1;                  // XCD pair per batch
    int r = ((g >> 3) << 1) | (g & 1);     // [0,576)
    int y = r & 63;
    int k = r >> 6;
    int t = threadIdx.x;

    if (t < 64) {
        int p = y * HW + t;
        const float* omb = om + ((size_t)b * 27) * NP;
        float o1 = omb[(size_t)k * NP + p];
        float o2 = omb[(size_t)(9 + k) * NP + p];
        float ml = omb[(size_t)(18 + k) * NP + p];
        float mask = 1.f / (1.f + expf(-ml));
        float sx = (float)t + (float)(k % 3) - 2.0f + o1;
        float sy = (float)y + (float)(k / 3) - 2.0f + o2;
        float x0f = floorf(sx), y0f = floorf(sy);
        float fx = sx - x0f, fy = sy - y0f;
        #pragma unroll
        for (int cy = 0; cy < 2; ++cy) {
            float yf = y0f + (float)cy;
            float wy = cy ? fy : 1.f - fy;
            #pragma unroll
            for (int cx = 0; cx < 2; ++cx) {
                float xf = x0f + (float)cx;
                float wx = cx ? fx : 1.f - fx;
                bool valid = (xf >= 0.f) && (xf <= 63.f) && (yf >= 0.f) && (yf <= 63.f);
                int xi = min(max((int)xf, 0), 63);
                int yi = min(max((int)yf, 0), 63);
                ci_l[t * 4 + cy * 2 + cx] = yi * HW + xi;
                cw_l[t * 4 + cy * 2 + cx] = valid ? wx * wy * mask : 0.f;
            }
        }
    }
    __syncthreads();

    int lane = t & 63;
    int w = t >> 6;
    const ushort_t* xtb = xt + ((size_t)b * NP) * NC + lane * 4;
    ushort_t* sbb = sb + ((size_t)b * NP + (size_t)y * HW) * NCK + k * NC + lane * 4;

    #pragma unroll 1
    for (int i = 0; i < 16; ++i) {
        int pl = w * 16 + i;
        int4   id = *(const int4*)&ci_l[pl * 4];
        float4 cw = *(const float4*)&cw_l[pl * 4];
        uint2 r0 = *(const uint2*)(xtb + (size_t)id.x * NC);
        uint2 r1 = *(const uint2*)(xtb + (size_t)id.y * NC);
        uint2 r2 = *(const uint2*)(xtb + (size_t)id.z * NC);
        uint2 r3 = *(const uint2*)(xtb + (size_t)id.w * NC);
        float s0 = cw.x*bf_lo(r0.x) + cw.y*bf_lo(r1.x) + cw.z*bf_lo(r2.x) + cw.w*bf_lo(r3.x);
        float s1 = cw.x*bf_hi(r0.x) + cw.y*bf_hi(r1.x) + cw.z*bf_hi(r2.x) + cw.w*bf_hi(r3.x);
        float s2 = cw.x*bf_lo(r0.y) + cw.y*bf_lo(r1.y) + cw.z*bf_lo(r2.y) + cw.w*bf_lo(r3.y);
        float s3 = cw.x*bf_hi(r0.y) + cw.y*bf_hi(r1.y) + cw.z*bf_hi(r2.y) + cw.w*bf_hi(r3.y);
        uint32 p0 = f2bf(s0) | (f2bf(s1) << 16);
        uint32 p1 = f2bf(s2) | (f2bf(s3) << 16);
        *(uint2*)(sbb + (size_t)pl * NCK) = make_uint2(p0, p1);
    }
}

// ---------------------------------------------------------------- gemm2
// Block=(b,ot,pt): 128o x 64p tile, grid 512 (2 blocks/CU). 4 waves:
// wave (wo,wp) = 64o x 32p -> 4x2 frags. LDS rows 80B padded, double-buffered.
__global__ __launch_bounds__(256) void gemm2(const ushort_t* __restrict__ wta,
                                             const ushort_t* __restrict__ sb,
                                             const float* __restrict__ bias,
                                             float* __restrict__ out) {
    __shared__ __align__(16) char lds[2 * 15360];   // [buf][A 10240 | B 5120]
    int bid = blockIdx.x;           // b*128 + ot*64 + pt
    int pt = bid & 63;
    int ot = (bid >> 6) & 1;
    int b  = bid >> 7;
    int t = threadIdx.x;
    int lane = t & 63;
    int w = t >> 6;
    int wo = w & 1;
    int wp = w >> 1;
    int r16 = lane & 15;
    int g   = lane >> 4;

    const char* Abase = (const char*)wta + (size_t)(ot * 128) * ROWB;
    const char* Bbase = (const char*)sb + (size_t)b * NP * ROWB
                                        + (size_t)(pt * 64) * ROWB;
    // 15 staging chunks of 1024B: j<10 -> A (10240B), j>=10 -> B (5120B).
    const char* srcp[4]; int dstp[4]; bool jv[4];
    #pragma unroll
    for (int jj = 0; jj < 4; ++jj) {
        int j = w + jj * 4;
        jv[jj] = (j < 15);
        if (j < 10) {
            int d = j * 1024 + lane * 16;
            int row = d / 80, col = d - row * 80;
            if (col >= 64) col = 48;
            srcp[jj] = Abase + (size_t)row * ROWB + col;
            dstp[jj] = j * 1024;
        } else if (j < 15) {
            int j2 = j - 10;
            int d = j2 * 1024 + lane * 16;
            int row = d / 80, col = d - row * 80;
            if (col >= 64) col = 48;
            srcp[jj] = Bbase + (size_t)row * ROWB + col;
            dstp[jj] = 10240 + j2 * 1024;
        } else { srcp[jj] = Abase; dstp[jj] = 0; }
    }

    int aoff[4], boff[2];
    #pragma unroll
    for (int f = 0; f < 4; ++f)
        aoff[f] = (wo * 64 + f * 16 + r16) * 80 + g * 16;
    #pragma unroll
    for (int f = 0; f < 2; ++f)
        boff[f] = 10240 + (wp * 32 + f * 16 + r16) * 80 + g * 16;

    f32x4 acc[4][2];
    #pragma unroll
    for (int fo = 0; fo < 4; ++fo)
        #pragma unroll
        for (int fp = 0; fp < 2; ++fp) acc[fo][fp] = (f32x4){0.f, 0.f, 0.f, 0.f};

    #pragma unroll
    for (int jj = 0; jj < 4; ++jj)
        if (jv[jj]) gload16(srcp[jj], lds + dstp[jj]);
    __syncthreads();

    for (int kt = 0; kt < NKT; ++kt) {
        int q = kt & 1;
        if (kt + 1 < NKT) {
            char* dst = lds + (q ^ 1) * 15360;
            size_t ko = (size_t)(kt + 1) * 64;
            #pragma unroll
            for (int jj = 0; jj < 4; ++jj)
                if (jv[jj]) gload16(srcp[jj] + ko, dst + dstp[jj]);
        }
        const char* buf = lds + q * 15360;
        short8 av[4], bv[2];
        #pragma unroll
        for (int f = 0; f < 4; ++f) av[f] = *(const short8*)(buf + aoff[f]);
        #pragma unroll
        for (int f = 0; f < 2; ++f) bv[f] = *(const short8*)(buf + boff[f]);
        #pragma unroll
        for (int fo = 0; fo < 4; ++fo)
            #pragma unroll
            for (int fp = 0; fp < 2; ++fp)
                acc[fo][fp] = __builtin_amdgcn_mfma_f32_16x16x32_bf16(
                    av[fo], bv[fp], acc[fo][fp], 0, 0, 0);
        __syncthreads();
    }

    // C/D: col(p)=lane&15, row(o)=(lane>>4)*4+reg
    int obase = ot * 128 + wo * 64;
    int pbase = pt * 64 + wp * 32 + r16;
    float* outb = out + ((size_t)b * NOC) * NP;
    #pragma unroll
    for (int fo = 0; fo < 4; ++fo) {
        #pragma unroll
        for (int rr = 0; rr < 4; ++rr) {
            int o = obase + fo * 16 + g * 4 + rr;
            float bb = bias[o];
            #pragma unroll
            for (int fp = 0; fp < 2; ++fp)
                outb[(size_t)o * NP + pbase + fp * 16] = acc[fo][fp][rr] + bb;
        }
    }
}

// ---------------------------------------------------------------- launch
extern "C" void kernel_launch(void* const* d_in, const int* in_sizes, int n_in,
                              void* d_out, int out_size, void* d_ws, size_t ws_size,
                              hipStream_t stream) {
    const float* x     = (const float*)d_in[0];
    const float* ow    = (const float*)d_in[1];
    const float* obias = (const float*)d_in[2];
    const float* wgt   = (const float*)d_in[3];
    const float* bias  = (const float*)d_in[4];
    float* out = (float*)d_out;

    char* ws = (char*)d_ws;
    float*    om   = (float*)ws;                     //  1,769,472 B
    float*    owt  = (float*)(ws + 1769472);         //    248,832 B
    ushort_t* wta  = (ushort_t*)(ws + 2018304);      //  1,179,648 B
    ushort_t* xt   = (ushort_t*)(ws + 3197952);      //  8,388,608 B
    ushort_t* sbuf = (ushort_t*)(ws + 11586560);     // 75,497,472 B (tot ~87 MB)

    hipLaunchKernelGGL(wprep_A,    dim3(2304), dim3(256), 0, stream, wgt, wta);
    hipLaunchKernelGGL(owt_prep,   dim3(243),  dim3(256), 0, stream, ow, owt);
    hipLaunchKernelGGL(om_init,    dim3(1728), dim3(256), 0, stream, obias, om);
    hipLaunchKernelGGL(xprep,      dim3(2048), dim3(256), 0, stream, x, xt);
    hipLaunchKernelGGL(offs_conv3, dim3(2048), dim3(256), 0, stream, x, owt, om);
    hipLaunchKernelGGL(gather2,    dim3(2304), dim3(256), 0, stream, xt, om, sbuf);
    hipLaunchKernelGGL(gemm2,      dim3(512),  dim3(256), 0, stream, wta, sbuf, bias, out);
}

// Round 6
// 173.596 us; speedup vs baseline: 5.8053x; 1.4431x over previous
//
#include <hip/hip_runtime.h>

// DCNv2 B=4,C=256,H=W=64,OC=256,K=9. Pipeline:
//   wprep_A  : weight -> WtA[o][ck] bf16 (ck=k*256+c)
//   owb_prep : offset_w -> owb[k][32ch pad][256c] bf16
//   xprep2   : x NCHW f32 -> xT[b][p][c] bf16 (NHWC), LDS-transposed coalesced
//   offs_mfma: offset conv as 9-shift MFMA GEMM (M=32,N=64,K=2304) -> om f32
//   gather2  : coords once per (k,p); lane=c coalesced bf16 gather -> S[b][p][ck]
//   gemm2    : bf16 MFMA 16x16x32, 128o x 64p tiles, grid 512

#define NB 4
#define NC 256
#define HW 64
#define NP 4096
#define NOC 256
#define NCK 2304
#define NKT 72              // K tiles of 32
#define ROWB 4608           // bytes per ck-row (2304 * 2B)

typedef __attribute__((ext_vector_type(8))) short short8;
typedef __attribute__((ext_vector_type(4))) float f32x4;
typedef unsigned short ushort_t;
typedef unsigned int uint32;

__device__ __forceinline__ void gload16(const void* g, void* l) {
    __builtin_amdgcn_global_load_lds(
        (const __attribute__((address_space(1))) unsigned int*)g,
        (__attribute__((address_space(3))) unsigned int*)l, 16, 0, 0);
}

__device__ __forceinline__ uint32 f2bf(float v) {
    uint32 b = __float_as_uint(v);
    return (b + 0x7FFFu + ((b >> 16) & 1u)) >> 16;   // RNE
}
__device__ __forceinline__ float bf_lo(uint32 u) { return __uint_as_float(u << 16); }
__device__ __forceinline__ float bf_hi(uint32 u) { return __uint_as_float(u & 0xFFFF0000u); }

// ---------------------------------------------------------------- wprep_A
__global__ __launch_bounds__(256) void wprep_A(const float* __restrict__ w,
                                               ushort_t* __restrict__ wta) {
    int e = blockIdx.x * 256 + threadIdx.x;     // < 256*2304
    int o  = e / NCK;
    int ck = e - o * NCK;
    int c = ck & 255;
    int k = ck >> 8;
    wta[e] = (ushort_t)f2bf(w[o * NCK + c * 9 + k]);
}

// ---------------------------------------------------------------- owb_prep
// owb[(k*32+ch)*256 + c] = bf16(offset_w[ch][c][ki][kj]), ch 27..31 zero-pad.
__global__ __launch_bounds__(256) void owb_prep(const float* __restrict__ ow,
                                                ushort_t* __restrict__ owb) {
    int e = blockIdx.x * 256 + threadIdx.x;     // < 73728
    int c = e & 255;
    int r = e >> 8;          // k*32 + ch
    int ch = r & 31;
    int k = r >> 5;
    float v = 0.f;
    if (ch < 27) v = ow[(ch * NC + c) * 9 + k];
    owb[e] = (ushort_t)f2bf(v);
}

// ---------------------------------------------------------------- xprep2
// Coalesced NCHW f32 -> NHWC bf16 via LDS transpose. Block = [64 c][128 p].
__global__ __launch_bounds__(256) void xprep2(const float* __restrict__ x,
                                              ushort_t* __restrict__ xt) {
    __shared__ float tr[128 * 65];    // 33280 B
    int bid = blockIdx.x;             // b*128 + cc*32 + pt
    int pt = bid & 31;
    int cc = (bid >> 5) & 3;
    int b  = bid >> 7;
    int t = threadIdx.x;
    int c0 = cc * 64;

    const float* xb = x + ((size_t)(b * NC + c0)) * NP + pt * 128;
    #pragma unroll
    for (int pass = 0; pass < 8; ++pass) {
        int c  = pass * 8 + (t >> 5);
        int p4 = (t & 31) * 4;
        float4 v = *(const float4*)(xb + (size_t)c * NP + p4);
        tr[(p4 + 0) * 65 + c] = v.x;
        tr[(p4 + 1) * 65 + c] = v.y;
        tr[(p4 + 2) * 65 + c] = v.z;
        tr[(p4 + 3) * 65 + c] = v.w;
    }
    __syncthreads();
    ushort_t* xto = xt + ((size_t)b * NP + pt * 128) * NC + c0;
    #pragma unroll
    for (int pass = 0; pass < 4; ++pass) {
        int e = pass * 256 + t;
        int p = e >> 3, seg = e & 7;
        const float* rp = &tr[p * 65 + seg * 8];
        uint32 pk[4];
        #pragma unroll
        for (int h = 0; h < 4; ++h)
            pk[h] = f2bf(rp[2 * h]) | (f2bf(rp[2 * h + 1]) << 16);
        *(uint4*)(xto + (size_t)p * NC + seg * 8) = make_uint4(pk[0], pk[1], pk[2], pk[3]);
    }
}

// ---------------------------------------------------------------- offs_mfma
// om[b][27][y*64+p] = bias + sum_k W_k[27][256] . X[y+dy-1][p+dx-1][256].
// Block=(b,y). LDS: B-halo tile [3dy][66xx][64c] rows padded to 144B (28512B)
// + A slices [9k][32ch][64c] (36864B) = 65376B. Waves split shifts s%4==w;
// f32 LDS reduce at the end (region reused).
__global__ __launch_bounds__(256) void offs_mfma(const ushort_t* __restrict__ xt,
                                                 const ushort_t* __restrict__ owb,
                                                 const float* __restrict__ obias,
                                                 float* __restrict__ om) {
    __shared__ __align__(16) char lds[65376];
    int bid = blockIdx.x;        // b*64 + y
    int y = bid & 63;
    int b = bid >> 6;
    int t = threadIdx.x;
    int lane = t & 63;
    int w = t >> 6;
    int r16 = lane & 15;
    int g   = lane >> 4;

    f32x4 acc[2][4];
    #pragma unroll
    for (int mf = 0; mf < 2; ++mf)
        #pragma unroll
        for (int nf = 0; nf < 4; ++nf) acc[mf][nf] = (f32x4){0.f, 0.f, 0.f, 0.f};

    const ushort_t* xtb = xt + ((size_t)b * NP) * NC;

    for (int cc = 0; cc < 4; ++cc) {
        int c0 = cc * 64;
        __syncthreads();
        // stage B halo tile: 198 rows (dy,xx) x 8 segs of 16B, zero OOB
        for (int e = t; e < 1584; e += 256) {
            int rr = e >> 3, seg = e & 7;
            int dy = (rr >= 132) ? 2 : (rr >= 66 ? 1 : 0);
            int xx = rr - dy * 66;
            int ys = y + dy - 1;
            int xs = xx - 1;
            uint4 v = make_uint4(0, 0, 0, 0);
            if (ys >= 0 && ys < 64 && xs >= 0 && xs < 64)
                v = *(const uint4*)(xtb + ((ys << 6) + xs) * NC + c0 + seg * 8);
            *(uint4*)(lds + rr * 144 + seg * 16) = v;
        }
        // stage A: 9 slices x 32 ch x 64 c
        for (int e = t; e < 2304; e += 256) {
            int row = e >> 3;        // k*32 + ch
            int seg = e & 7;
            uint4 v = *(const uint4*)(owb + (row << 8) + c0 + seg * 8);
            *(uint4*)(lds + 28512 + (row << 7) + seg * 16) = v;
        }
        __syncthreads();
        for (int s = w; s < 9; s += 4) {
            int dy = (s >= 6) ? 2 : (s >= 3 ? 1 : 0);
            int dx = s - dy * 3;
            const char* Ab = lds + 28512 + s * 4096;
            #pragma unroll
            for (int ks = 0; ks < 2; ++ks) {
                short8 a0 = *(const short8*)(Ab + r16 * 128 + ks * 64 + g * 16);
                short8 a1 = *(const short8*)(Ab + (16 + r16) * 128 + ks * 64 + g * 16);
                #pragma unroll
                for (int nf = 0; nf < 4; ++nf) {
                    short8 bv = *(const short8*)(lds +
                        (dy * 66 + nf * 16 + r16 + dx) * 144 + ks * 64 + g * 16);
                    acc[0][nf] = __builtin_amdgcn_mfma_f32_16x16x32_bf16(
                        a0, bv, acc[0][nf], 0, 0, 0);
                    acc[1][nf] = __builtin_amdgcn_mfma_f32_16x16x32_bf16(
                        a1, bv, acc[1][nf], 0, 0, 0);
                }
            }
        }
    }
    __syncthreads();
    // cross-wave reduce: red[w][32 ch][64 p] f32 (reuses tile region)
    float* red = (float*)lds;
    #pragma unroll
    for (int mf = 0; mf < 2; ++mf)
        #pragma unroll
        for (int nf = 0; nf < 4; ++nf)
            #pragma unroll
            for (int r = 0; r < 4; ++r) {
                int ch = mf * 16 + g * 4 + r;
                int p  = nf * 16 + r16;
                red[((w * 32 + ch) << 6) + p] = acc[mf][nf][r];
            }
    __syncthreads();
    for (int e = t; e < 27 * 64; e += 256) {
        int ch = e >> 6, p = e & 63;
        float sres = red[(ch << 6) + p] + red[((32 + ch) << 6) + p]
                   + red[((64 + ch) << 6) + p] + red[((96 + ch) << 6) + p]
                   + obias[ch];
        om[((size_t)(b * 27 + ch)) * NP + (y << 6) + p] = sres;
    }
}

// ---------------------------------------------------------------- gather2
// Block=(b,k,y) with XCD affinity: batch b pinned to XCDs {2b,2b+1}.
__global__ __launch_bounds__(256) void gather2(const ushort_t* __restrict__ xt,
                                               const float* __restrict__ om,
                                               ushort_t* __restrict__ sb) {
    __shared__ __align__(16) int   ci_l[64 * 4];
    __shared__ __align__(16) float cw_l[64 * 4];
    int g = blockIdx.x;                    // 2304 blocks
    int b = (g & 7) >> 1;                  // XCD pair per batch
    int r = ((g >> 3) << 1) | (g & 1);     // [0,576)
    int y = r & 63;
    int k = r >> 6;
    int t = threadIdx.x;

    if (t < 64) {
        int p = y * HW + t;
        const float* omb = om + ((size_t)b * 27) * NP;
        float o1 = omb[(size_t)k * NP + p];
        float o2 = omb[(size_t)(9 + k) * NP + p];
        float ml = omb[(size_t)(18 + k) * NP + p];
        float mask = 1.f / (1.f + expf(-ml));
        float sx = (float)t + (float)(k % 3) - 2.0f + o1;
        float sy = (float)y + (float)(k / 3) - 2.0f + o2;
        float x0f = floorf(sx), y0f = floorf(sy);
        float fx = sx - x0f, fy = sy - y0f;
        #pragma unroll
        for (int cy = 0; cy < 2; ++cy) {
            float yf = y0f + (float)cy;
            float wy = cy ? fy : 1.f - fy;
            #pragma unroll
            for (int cx = 0; cx < 2; ++cx) {
                float xf = x0f + (float)cx;
                float wx = cx ? fx : 1.f - fx;
                bool valid = (xf >= 0.f) && (xf <= 63.f) && (yf >= 0.f) && (yf <= 63.f);
                int xi = min(max((int)xf, 0), 63);
                int yi = min(max((int)yf, 0), 63);
                ci_l[t * 4 + cy * 2 + cx] = yi * HW + xi;
                cw_l[t * 4 + cy * 2 + cx] = valid ? wx * wy * mask : 0.f;
            }
        }
    }
    __syncthreads();

    int lane = t & 63;
    int w = t >> 6;
    const ushort_t* xtb = xt + ((size_t)b * NP) * NC + lane * 4;
    ushort_t* sbb = sb + ((size_t)b * NP + (size_t)y * HW) * NCK + k * NC + lane * 4;

    #pragma unroll 1
    for (int i = 0; i < 16; ++i) {
        int pl = w * 16 + i;
        int4   id = *(const int4*)&ci_l[pl * 4];
        float4 cw = *(const float4*)&cw_l[pl * 4];
        uint2 r0 = *(const uint2*)(xtb + (size_t)id.x * NC);
        uint2 r1 = *(const uint2*)(xtb + (size_t)id.y * NC);
        uint2 r2 = *(const uint2*)(xtb + (size_t)id.z * NC);
        uint2 r3 = *(const uint2*)(xtb + (size_t)id.w * NC);
        float s0 = cw.x*bf_lo(r0.x) + cw.y*bf_lo(r1.x) + cw.z*bf_lo(r2.x) + cw.w*bf_lo(r3.x);
        float s1 = cw.x*bf_hi(r0.x) + cw.y*bf_hi(r1.x) + cw.z*bf_hi(r2.x) + cw.w*bf_hi(r3.x);
        float s2 = cw.x*bf_lo(r0.y) + cw.y*bf_lo(r1.y) + cw.z*bf_lo(r2.y) + cw.w*bf_lo(r3.y);
        float s3 = cw.x*bf_hi(r0.y) + cw.y*bf_hi(r1.y) + cw.z*bf_hi(r2.y) + cw.w*bf_hi(r3.y);
        uint32 p0 = f2bf(s0) | (f2bf(s1) << 16);
        uint32 p1 = f2bf(s2) | (f2bf(s3) << 16);
        *(uint2*)(sbb + (size_t)pl * NCK) = make_uint2(p0, p1);
    }
}

// ---------------------------------------------------------------- gemm2
// Block=(b,ot,pt): 128o x 64p tile, grid 512 (2 blocks/CU). 4 waves:
// wave (wo,wp) = 64o x 32p -> 4x2 frags. LDS rows 80B padded, double-buffered.
__global__ __launch_bounds__(256) void gemm2(const ushort_t* __restrict__ wta,
                                             const ushort_t* __restrict__ sb,
                                             const float* __restrict__ bias,
                                             float* __restrict__ out) {
    __shared__ __align__(16) char lds[2 * 15360];   // [buf][A 10240 | B 5120]
    int bid = blockIdx.x;           // b*128 + ot*64 + pt
    int pt = bid & 63;
    int ot = (bid >> 6) & 1;
    int b  = bid >> 7;
    int t = threadIdx.x;
    int lane = t & 63;
    int w = t >> 6;
    int wo = w & 1;
    int wp = w >> 1;
    int r16 = lane & 15;
    int g   = lane >> 4;

    const char* Abase = (const char*)wta + (size_t)(ot * 128) * ROWB;
    const char* Bbase = (const char*)sb + (size_t)b * NP * ROWB
                                        + (size_t)(pt * 64) * ROWB;
    const char* srcp[4]; int dstp[4]; bool jv[4];
    #pragma unroll
    for (int jj = 0; jj < 4; ++jj) {
        int j = w + jj * 4;
        jv[jj] = (j < 15);
        if (j < 10) {
            int d = j * 1024 + lane * 16;
            int row = d / 80, col = d - row * 80;
            if (col >= 64) col = 48;
            srcp[jj] = Abase + (size_t)row * ROWB + col;
            dstp[jj] = j * 1024;
        } else if (j < 15) {
            int j2 = j - 10;
            int d = j2 * 1024 + lane * 16;
            int row = d / 80, col = d - row * 80;
            if (col >= 64) col = 48;
            srcp[jj] = Bbase + (size_t)row * ROWB + col;
            dstp[jj] = 10240 + j2 * 1024;
        } else { srcp[jj] = Abase; dstp[jj] = 0; }
    }

    int aoff[4], boff[2];
    #pragma unroll
    for (int f = 0; f < 4; ++f)
        aoff[f] = (wo * 64 + f * 16 + r16) * 80 + g * 16;
    #pragma unroll
    for (int f = 0; f < 2; ++f)
        boff[f] = 10240 + (wp * 32 + f * 16 + r16) * 80 + g * 16;

    f32x4 acc[4][2];
    #pragma unroll
    for (int fo = 0; fo < 4; ++fo)
        #pragma unroll
        for (int fp = 0; fp < 2; ++fp) acc[fo][fp] = (f32x4){0.f, 0.f, 0.f, 0.f};

    #pragma unroll
    for (int jj = 0; jj < 4; ++jj)
        if (jv[jj]) gload16(srcp[jj], lds + dstp[jj]);
    __syncthreads();

    for (int kt = 0; kt < NKT; ++kt) {
        int q = kt & 1;
        if (kt + 1 < NKT) {
            char* dst = lds + (q ^ 1) * 15360;
            size_t ko = (size_t)(kt + 1) * 64;
            #pragma unroll
            for (int jj = 0; jj < 4; ++jj)
                if (jv[jj]) gload16(srcp[jj] + ko, dst + dstp[jj]);
        }
        const char* buf = lds + q * 15360;
        short8 av[4], bv[2];
        #pragma unroll
        for (int f = 0; f < 4; ++f) av[f] = *(const short8*)(buf + aoff[f]);
        #pragma unroll
        for (int f = 0; f < 2; ++f) bv[f] = *(const short8*)(buf + boff[f]);
        #pragma unroll
        for (int fo = 0; fo < 4; ++fo)
            #pragma unroll
            for (int fp = 0; fp < 2; ++fp)
                acc[fo][fp] = __builtin_amdgcn_mfma_f32_16x16x32_bf16(
                    av[fo], bv[fp], acc[fo][fp], 0, 0, 0);
        __syncthreads();
    }

    int obase = ot * 128 + wo * 64;
    int pbase = pt * 64 + wp * 32 + r16;
    float* outb = out + ((size_t)b * NOC) * NP;
    #pragma unroll
    for (int fo = 0; fo < 4; ++fo) {
        #pragma unroll
        for (int rr = 0; rr < 4; ++rr) {
            int o = obase + fo * 16 + g * 4 + rr;
            float bb = bias[o];
            #pragma unroll
            for (int fp = 0; fp < 2; ++fp)
                outb[(size_t)o * NP + pbase + fp * 16] = acc[fo][fp][rr] + bb;
        }
    }
}

// ---------------------------------------------------------------- launch
extern "C" void kernel_launch(void* const* d_in, const int* in_sizes, int n_in,
                              void* d_out, int out_size, void* d_ws, size_t ws_size,
                              hipStream_t stream) {
    const float* x     = (const float*)d_in[0];
    const float* ow    = (const float*)d_in[1];
    const float* obias = (const float*)d_in[2];
    const float* wgt   = (const float*)d_in[3];
    const float* bias  = (const float*)d_in[4];
    float* out = (float*)d_out;

    char* ws = (char*)d_ws;
    float*    om   = (float*)ws;                     //  1,769,472 B
    ushort_t* owb  = (ushort_t*)(ws + 1769472);      //    147,456 B
    ushort_t* wta  = (ushort_t*)(ws + 1916928);      //  1,179,648 B
    ushort_t* xt   = (ushort_t*)(ws + 3096576);      //  8,388,608 B
    ushort_t* sbuf = (ushort_t*)(ws + 11485184);     // 75,497,472 B (tot ~87 MB)

    hipLaunchKernelGGL(wprep_A,   dim3(2304), dim3(256), 0, stream, wgt, wta);
    hipLaunchKernelGGL(owb_prep,  dim3(288),  dim3(256), 0, stream, ow, owb);
    hipLaunchKernelGGL(xprep2,    dim3(512),  dim3(256), 0, stream, x, xt);
    hipLaunchKernelGGL(offs_mfma, dim3(256),  dim3(256), 0, stream, xt, owb, obias, om);
    hipLaunchKernelGGL(gather2,   dim3(2304), dim3(256), 0, stream, xt, om, sbuf);
    hipLaunchKernelGGL(gemm2,     dim3(512),  dim3(256), 0, stream, wta, sbuf, bias, out);
}

// Round 7
// 168.881 us; speedup vs baseline: 5.9674x; 1.0279x over previous
//
#include <hip/hip_runtime.h>

// DCNv2 B=4,C=256,H=W=64,OC=256,K=9. Pipeline:
//   wprep_A   : weight -> WtA[o][ck] bf16 (ck=k*256+c)
//   owb_prep  : offset_w -> owb[k][32ch pad][256c] bf16
//   om_init   : om = obias broadcast
//   xprep2    : x NCHW f32 -> xT[b][p][c] bf16 (NHWC), LDS-transposed coalesced
//   offs_mfma2: offset conv as 9-shift MFMA GEMM, c-split x2, atomic reduce -> om
//   gather3   : coords once per (k,p); 8c-per-lane uint4 gather -> S[b][p][ck]
//   gemm2     : bf16 MFMA 16x16x32, 128o x 64p tiles, grid 512

#define NB 4
#define NC 256
#define HW 64
#define NP 4096
#define NOC 256
#define NCK 2304
#define NKT 72              // K tiles of 32
#define ROWB 4608           // bytes per ck-row (2304 * 2B)

typedef __attribute__((ext_vector_type(8))) short short8;
typedef __attribute__((ext_vector_type(4))) float f32x4;
typedef unsigned short ushort_t;
typedef unsigned int uint32;

__device__ __forceinline__ void gload16(const void* g, void* l) {
    __builtin_amdgcn_global_load_lds(
        (const __attribute__((address_space(1))) unsigned int*)g,
        (__attribute__((address_space(3))) unsigned int*)l, 16, 0, 0);
}

__device__ __forceinline__ uint32 f2bf(float v) {
    uint32 b = __float_as_uint(v);
    return (b + 0x7FFFu + ((b >> 16) & 1u)) >> 16;   // RNE
}
__device__ __forceinline__ float bf_lo(uint32 u) { return __uint_as_float(u << 16); }
__device__ __forceinline__ float bf_hi(uint32 u) { return __uint_as_float(u & 0xFFFF0000u); }

// ---------------------------------------------------------------- wprep_A
__global__ __launch_bounds__(256) void wprep_A(const float* __restrict__ w,
                                               ushort_t* __restrict__ wta) {
    int e = blockIdx.x * 256 + threadIdx.x;     // < 256*2304
    int o  = e / NCK;
    int ck = e - o * NCK;
    int c = ck & 255;
    int k = ck >> 8;
    wta[e] = (ushort_t)f2bf(w[o * NCK + c * 9 + k]);
}

// ---------------------------------------------------------------- owb_prep
// owb[(k*32+ch)*256 + c] = bf16(offset_w[ch][c][ki][kj]), ch 27..31 zero-pad.
__global__ __launch_bounds__(256) void owb_prep(const float* __restrict__ ow,
                                                ushort_t* __restrict__ owb) {
    int e = blockIdx.x * 256 + threadIdx.x;     // < 73728
    int c = e & 255;
    int r = e >> 8;          // k*32 + ch
    int ch = r & 31;
    int k = r >> 5;
    float v = 0.f;
    if (ch < 27) v = ow[(ch * NC + c) * 9 + k];
    owb[e] = (ushort_t)f2bf(v);
}

// ---------------------------------------------------------------- om_init
__global__ __launch_bounds__(256) void om_init(const float* __restrict__ obias,
                                               float* __restrict__ om) {
    int g = blockIdx.x * 256 + threadIdx.x;     // < 4*27*4096
    int r = g >> 12;
    int ch = r % 27;
    om[g] = obias[ch];
}

// ---------------------------------------------------------------- xprep2
// Coalesced NCHW f32 -> NHWC bf16 via LDS transpose. Block = [64 c][128 p].
__global__ __launch_bounds__(256) void xprep2(const float* __restrict__ x,
                                              ushort_t* __restrict__ xt) {
    __shared__ float tr[128 * 65];    // 33280 B
    int bid = blockIdx.x;             // b*128 + cc*32 + pt
    int pt = bid & 31;
    int cc = (bid >> 5) & 3;
    int b  = bid >> 7;
    int t = threadIdx.x;
    int c0 = cc * 64;

    const float* xb = x + ((size_t)(b * NC + c0)) * NP + pt * 128;
    #pragma unroll
    for (int pass = 0; pass < 8; ++pass) {
        int c  = pass * 8 + (t >> 5);
        int p4 = (t & 31) * 4;
        float4 v = *(const float4*)(xb + (size_t)c * NP + p4);
        tr[(p4 + 0) * 65 + c] = v.x;
        tr[(p4 + 1) * 65 + c] = v.y;
        tr[(p4 + 2) * 65 + c] = v.z;
        tr[(p4 + 3) * 65 + c] = v.w;
    }
    __syncthreads();
    ushort_t* xto = xt + ((size_t)b * NP + pt * 128) * NC + c0;
    #pragma unroll
    for (int pass = 0; pass < 4; ++pass) {
        int e = pass * 256 + t;
        int p = e >> 3, seg = e & 7;
        const float* rp = &tr[p * 65 + seg * 8];
        uint32 pk[4];
        #pragma unroll
        for (int h = 0; h < 4; ++h)
            pk[h] = f2bf(rp[2 * h]) | (f2bf(rp[2 * h + 1]) << 16);
        *(uint4*)(xto + (size_t)p * NC + seg * 8) = make_uint4(pk[0], pk[1], pk[2], pk[3]);
    }
}

// ---------------------------------------------------------------- offs_mfma2
// om[b][27][y*64+p] += sum over this block's half of c of shift-GEMM.
// Block=(b,y,h): h picks c-chunks {2h,2h+1} (128 c). Grid 512 = 2 blocks/CU.
__global__ __launch_bounds__(256) void offs_mfma2(const ushort_t* __restrict__ xt,
                                                  const ushort_t* __restrict__ owb,
                                                  float* __restrict__ om) {
    __shared__ __align__(16) char lds[65376];
    int bid = blockIdx.x;        // b*128 + y*2 + h
    int h = bid & 1;
    int y = (bid >> 1) & 63;
    int b = bid >> 7;
    int t = threadIdx.x;
    int lane = t & 63;
    int w = t >> 6;
    int r16 = lane & 15;
    int g   = lane >> 4;

    f32x4 acc[2][4];
    #pragma unroll
    for (int mf = 0; mf < 2; ++mf)
        #pragma unroll
        for (int nf = 0; nf < 4; ++nf) acc[mf][nf] = (f32x4){0.f, 0.f, 0.f, 0.f};

    const ushort_t* xtb = xt + ((size_t)b * NP) * NC;

    for (int ccc = 0; ccc < 2; ++ccc) {
        int c0 = (h * 2 + ccc) * 64;
        __syncthreads();
        // stage B halo tile: 198 rows (dy,xx) x 8 segs of 16B, zero OOB
        for (int e = t; e < 1584; e += 256) {
            int rr = e >> 3, seg = e & 7;
            int dy = (rr >= 132) ? 2 : (rr >= 66 ? 1 : 0);
            int xx = rr - dy * 66;
            int ys = y + dy - 1;
            int xs = xx - 1;
            uint4 v = make_uint4(0, 0, 0, 0);
            if (ys >= 0 && ys < 64 && xs >= 0 && xs < 64)
                v = *(const uint4*)(xtb + ((ys << 6) + xs) * NC + c0 + seg * 8);
            *(uint4*)(lds + rr * 144 + seg * 16) = v;
        }
        // stage A: 9 slices x 32 ch x 64 c
        for (int e = t; e < 2304; e += 256) {
            int row = e >> 3;        // k*32 + ch
            int seg = e & 7;
            uint4 v = *(const uint4*)(owb + (row << 8) + c0 + seg * 8);
            *(uint4*)(lds + 28512 + (row << 7) + seg * 16) = v;
        }
        __syncthreads();
        for (int s = w; s < 9; s += 4) {
            int dy = (s >= 6) ? 2 : (s >= 3 ? 1 : 0);
            int dx = s - dy * 3;
            const char* Ab = lds + 28512 + s * 4096;
            #pragma unroll
            for (int ks = 0; ks < 2; ++ks) {
                short8 a0 = *(const short8*)(Ab + r16 * 128 + ks * 64 + g * 16);
                short8 a1 = *(const short8*)(Ab + (16 + r16) * 128 + ks * 64 + g * 16);
                #pragma unroll
                for (int nf = 0; nf < 4; ++nf) {
                    short8 bv = *(const short8*)(lds +
                        (dy * 66 + nf * 16 + r16 + dx) * 144 + ks * 64 + g * 16);
                    acc[0][nf] = __builtin_amdgcn_mfma_f32_16x16x32_bf16(
                        a0, bv, acc[0][nf], 0, 0, 0);
                    acc[1][nf] = __builtin_amdgcn_mfma_f32_16x16x32_bf16(
                        a1, bv, acc[1][nf], 0, 0, 0);
                }
            }
        }
    }
    __syncthreads();
    // cross-wave reduce: red[w][32 ch][64 p] f32 (reuses tile region)
    float* red = (float*)lds;
    #pragma unroll
    for (int mf = 0; mf < 2; ++mf)
        #pragma unroll
        for (int nf = 0; nf < 4; ++nf)
            #pragma unroll
            for (int r = 0; r < 4; ++r) {
                int ch = mf * 16 + g * 4 + r;
                int p  = nf * 16 + r16;
                red[((w * 32 + ch) << 6) + p] = acc[mf][nf][r];
            }
    __syncthreads();
    for (int e = t; e < 27 * 64; e += 256) {
        int ch = e >> 6, p = e & 63;
        float sres = red[(ch << 6) + p] + red[((32 + ch) << 6) + p]
                   + red[((64 + ch) << 6) + p] + red[((96 + ch) << 6) + p];
        atomicAdd(&om[((size_t)(b * 27 + ch)) * NP + (y << 6) + p], sres);
    }
}

// ---------------------------------------------------------------- gather3
// Block=(b,k,y) with XCD affinity. Phase1: 64 threads compute row coords.
// Phase2: lane owns 8 c (uint4); half-waves process 2 p per iter, 8 iters.
// Corner loads: 32 lanes x 16B = 512B contiguous per corner row.
__global__ __launch_bounds__(256) void gather3(const ushort_t* __restrict__ xt,
                                               const float* __restrict__ om,
                                               ushort_t* __restrict__ sb) {
    __shared__ __align__(16) int4   ci_l[64];
    __shared__ __align__(16) float4 cw_l[64];
    int g = blockIdx.x;                    // 2304 blocks
    int b = (g & 7) >> 1;                  // XCD pair per batch
    int r = ((g >> 3) << 1) | (g & 1);     // [0,576)
    int y = r & 63;
    int k = r >> 6;
    int t = threadIdx.x;

    if (t < 64) {
        int p = y * HW + t;
        const float* omb = om + ((size_t)b * 27) * NP;
        float o1 = omb[(size_t)k * NP + p];
        float o2 = omb[(size_t)(9 + k) * NP + p];
        float ml = omb[(size_t)(18 + k) * NP + p];
        float mask = 1.f / (1.f + expf(-ml));
        float sx = (float)t + (float)(k % 3) - 2.0f + o1;
        float sy = (float)y + (float)(k / 3) - 2.0f + o2;
        float x0f = floorf(sx), y0f = floorf(sy);
        float fx = sx - x0f, fy = sy - y0f;
        int idv[4]; float wgt[4];
        #pragma unroll
        for (int cy = 0; cy < 2; ++cy) {
            float yf = y0f + (float)cy;
            float wy = cy ? fy : 1.f - fy;
            #pragma unroll
            for (int cx = 0; cx < 2; ++cx) {
                float xf = x0f + (float)cx;
                float wx = cx ? fx : 1.f - fx;
                bool valid = (xf >= 0.f) && (xf <= 63.f) && (yf >= 0.f) && (yf <= 63.f);
                int xi = min(max((int)xf, 0), 63);
                int yi = min(max((int)yf, 0), 63);
                idv[cy * 2 + cx] = yi * HW + xi;
                wgt[cy * 2 + cx] = valid ? wx * wy * mask : 0.f;
            }
        }
        ci_l[t] = make_int4(idv[0], idv[1], idv[2], idv[3]);
        cw_l[t] = make_float4(wgt[0], wgt[1], wgt[2], wgt[3]);
    }
    __syncthreads();

    int lane = t & 63;
    int w = t >> 6;
    int half = lane >> 5;
    int co = (lane & 31) * 8;
    const ushort_t* xtb = xt + ((size_t)b * NP) * NC + co;
    ushort_t* sbb = sb + ((size_t)b * NP + (size_t)y * HW) * NCK + k * NC + co;

    #pragma unroll 1
    for (int i = 0; i < 8; ++i) {
        int pl = w * 16 + half * 8 + i;
        int4   id = ci_l[pl];
        float4 cw = cw_l[pl];
        uint4 q0 = *(const uint4*)(xtb + (size_t)id.x * NC);
        uint4 q1 = *(const uint4*)(xtb + (size_t)id.y * NC);
        uint4 q2 = *(const uint4*)(xtb + (size_t)id.z * NC);
        uint4 q3 = *(const uint4*)(xtb + (size_t)id.w * NC);
        uint32 a0[4] = {q0.x, q0.y, q0.z, q0.w};
        uint32 a1[4] = {q1.x, q1.y, q1.z, q1.w};
        uint32 a2[4] = {q2.x, q2.y, q2.z, q2.w};
        uint32 a3[4] = {q3.x, q3.y, q3.z, q3.w};
        uint32 pk[4];
        #pragma unroll
        for (int d = 0; d < 4; ++d) {
            float lo = cw.x*bf_lo(a0[d]) + cw.y*bf_lo(a1[d])
                     + cw.z*bf_lo(a2[d]) + cw.w*bf_lo(a3[d]);
            float hi = cw.x*bf_hi(a0[d]) + cw.y*bf_hi(a1[d])
                     + cw.z*bf_hi(a2[d]) + cw.w*bf_hi(a3[d]);
            pk[d] = f2bf(lo) | (f2bf(hi) << 16);
        }
        *(uint4*)(sbb + (size_t)pl * NCK) = make_uint4(pk[0], pk[1], pk[2], pk[3]);
    }
}

// ---------------------------------------------------------------- gemm2
// Block=(b,ot,pt): 128o x 64p tile, grid 512 (2 blocks/CU). 4 waves:
// wave (wo,wp) = 64o x 32p -> 4x2 frags. LDS rows 80B padded, double-buffered.
__global__ __launch_bounds__(256) void gemm2(const ushort_t* __restrict__ wta,
                                             const ushort_t* __restrict__ sb,
                                             const float* __restrict__ bias,
                                             float* __restrict__ out) {
    __shared__ __align__(16) char lds[2 * 15360];   // [buf][A 10240 | B 5120]
    int bid = blockIdx.x;           // b*128 + ot*64 + pt
    int pt = bid & 63;
    int ot = (bid >> 6) & 1;
    int b  = bid >> 7;
    int t = threadIdx.x;
    int lane = t & 63;
    int w = t >> 6;
    int wo = w & 1;
    int wp = w >> 1;
    int r16 = lane & 15;
    int g   = lane >> 4;

    const char* Abase = (const char*)wta + (size_t)(ot * 128) * ROWB;
    const char* Bbase = (const char*)sb + (size_t)b * NP * ROWB
                                        + (size_t)(pt * 64) * ROWB;
    const char* srcp[4]; int dstp[4]; bool jv[4];
    #pragma unroll
    for (int jj = 0; jj < 4; ++jj) {
        int j = w + jj * 4;
        jv[jj] = (j < 15);
        if (j < 10) {
            int d = j * 1024 + lane * 16;
            int row = d / 80, col = d - row * 80;
            if (col >= 64) col = 48;
            srcp[jj] = Abase + (size_t)row * ROWB + col;
            dstp[jj] = j * 1024;
        } else if (j < 15) {
            int j2 = j - 10;
            int d = j2 * 1024 + lane * 16;
            int row = d / 80, col = d - row * 80;
            if (col >= 64) col = 48;
            srcp[jj] = Bbase + (size_t)row * ROWB + col;
            dstp[jj] = 10240 + j2 * 1024;
        } else { srcp[jj] = Abase; dstp[jj] = 0; }
    }

    int aoff[4], boff[2];
    #pragma unroll
    for (int f = 0; f < 4; ++f)
        aoff[f] = (wo * 64 + f * 16 + r16) * 80 + g * 16;
    #pragma unroll
    for (int f = 0; f < 2; ++f)
        boff[f] = 10240 + (wp * 32 + f * 16 + r16) * 80 + g * 16;

    f32x4 acc[4][2];
    #pragma unroll
    for (int fo = 0; fo < 4; ++fo)
        #pragma unroll
        for (int fp = 0; fp < 2; ++fp) acc[fo][fp] = (f32x4){0.f, 0.f, 0.f, 0.f};

    #pragma unroll
    for (int jj = 0; jj < 4; ++jj)
        if (jv[jj]) gload16(srcp[jj], lds + dstp[jj]);
    __syncthreads();

    for (int kt = 0; kt < NKT; ++kt) {
        int q = kt & 1;
        if (kt + 1 < NKT) {
            char* dst = lds + (q ^ 1) * 15360;
            size_t ko = (size_t)(kt + 1) * 64;
            #pragma unroll
            for (int jj = 0; jj < 4; ++jj)
                if (jv[jj]) gload16(srcp[jj] + ko, dst + dstp[jj]);
        }
        const char* buf = lds + q * 15360;
        short8 av[4], bv[2];
        #pragma unroll
        for (int f = 0; f < 4; ++f) av[f] = *(const short8*)(buf + aoff[f]);
        #pragma unroll
        for (int f = 0; f < 2; ++f) bv[f] = *(const short8*)(buf + boff[f]);
        #pragma unroll
        for (int fo = 0; fo < 4; ++fo)
            #pragma unroll
            for (int fp = 0; fp < 2; ++fp)
                acc[fo][fp] = __builtin_amdgcn_mfma_f32_16x16x32_bf16(
                    av[fo], bv[fp], acc[fo][fp], 0, 0, 0);
        __syncthreads();
    }

    int obase = ot * 128 + wo * 64;
    int pbase = pt * 64 + wp * 32 + r16;
    float* outb = out + ((size_t)b * NOC) * NP;
    #pragma unroll
    for (int fo = 0; fo < 4; ++fo) {
        #pragma unroll
        for (int rr = 0; rr < 4; ++rr) {
            int o = obase + fo * 16 + g * 4 + rr;
            float bb = bias[o];
            #pragma unroll
            for (int fp = 0; fp < 2; ++fp)
                outb[(size_t)o * NP + pbase + fp * 16] = acc[fo][fp][rr] + bb;
        }
    }
}

// ---------------------------------------------------------------- launch
extern "C" void kernel_launch(void* const* d_in, const int* in_sizes, int n_in,
                              void* d_out, int out_size, void* d_ws, size_t ws_size,
                              hipStream_t stream) {
    const float* x     = (const float*)d_in[0];
    const float* ow    = (const float*)d_in[1];
    const float* obias = (const float*)d_in[2];
    const float* wgt   = (const float*)d_in[3];
    const float* bias  = (const float*)d_in[4];
    float* out = (float*)d_out;

    char* ws = (char*)d_ws;
    float*    om   = (float*)ws;                     //  1,769,472 B
    ushort_t* owb  = (ushort_t*)(ws + 1769472);      //    147,456 B
    ushort_t* wta  = (ushort_t*)(ws + 1916928);      //  1,179,648 B
    ushort_t* xt   = (ushort_t*)(ws + 3096576);      //  8,388,608 B
    ushort_t* sbuf = (ushort_t*)(ws + 11485184);     // 75,497,472 B (tot ~87 MB)

    hipLaunchKernelGGL(wprep_A,    dim3(2304), dim3(256), 0, stream, wgt, wta);
    hipLaunchKernelGGL(owb_prep,   dim3(288),  dim3(256), 0, stream, ow, owb);
    hipLaunchKernelGGL(om_init,    dim3(1728), dim3(256), 0, stream, obias, om);
    hipLaunchKernelGGL(xprep2,     dim3(512),  dim3(256), 0, stream, x, xt);
    hipLaunchKernelGGL(offs_mfma2, dim3(512),  dim3(256), 0, stream, xt, owb, om);
    hipLaunchKernelGGL(gather3,    dim3(2304), dim3(256), 0, stream, xt, om, sbuf);
    hipLaunchKernelGGL(gemm2,      dim3(512),  dim3(256), 0, stream, wta, sbuf, bias, out);
}